// Round 14
// baseline (166.906 us; speedup 1.0000x reference)
//
#include <hip/hip_runtime.h>
#include <hip/hip_bf16.h>

// GAT layer on MI355X. Round 29: kill k_agg64's scheduling tail. The 52%
// occupancy across all agg rounds is now explained arithmetically: 1024-thr
// blocks (16 waves) hit the 32-waves/CU cap -> 2 blocks/CU resident (LDS
// would allow 3), 784 blocks -> 1.53 rounds -> half-empty straggler round.
// Fix: 512 threads (8 waves), SAME 64 nodes/block, SAME 784 blocks ->
// 3 blocks/CU (24 waves, LDS-capped), 784 ~= 768 resident = ~1.02 rounds.
// Phase A stride 512; phase B identical body, 8 nodes/wave; phase C: each
// wave does 2 of the 16 (tile,nt) MFMA units. k_mega/pack0 byte-identical
// to round 13 (asm pins kept). 3 dispatches.

#define NNODES 50000
#define NEDGES 800000
#define IN_F   256
#define HID    128
#define OUTF   64

#define PA_EPT   8
#define PA_EDGES (256 * PA_EPT)                          // 2048 edges/block
#define PA_NB    ((NEDGES + PA_EDGES - 1) / PA_EDGES)    // 391 blocks
#define NBKT     ((NNODES + 255) / 256)                  // 196 buckets (dst>>8)
#define BCAP     5120                                    // bucket capacity (lam=4082)
#define NSTRIP   (NNODES / 16)                           // 3125 strips
#define GB       ((NSTRIP + 3) / 4)                      // 782 gemm blocks

#define AGN      64                                      // nodes per agg block
#define AGSLOT   64                                      // per-node LDS slot cap (max deg ~45)
#define AGB      784                                     // 8 * 98 agg blocks (>= 782)

typedef unsigned short u16;
typedef unsigned long long u64;
typedef __bf16 bf16x8 __attribute__((ext_vector_type(8)));
typedef float  f32x4  __attribute__((ext_vector_type(4)));

__device__ __forceinline__ u16 f2b(float f) {
    union { float f; unsigned u; } v; v.f = f;
    unsigned u = v.u;
    return (u16)((u + 0x7fffu + ((u >> 16) & 1u)) >> 16);  // RNE fp32->bf16
}
__device__ __forceinline__ float b2f_lo(unsigned v) {
    union { unsigned u; float f; } c; c.u = (v & 0xffffu) << 16; return c.f;
}
__device__ __forceinline__ float b2f_hi(unsigned v) {
    union { unsigned u; float f; } c; c.u = v & 0xffff0000u; return c.f;
}
__device__ __forceinline__ float lrelu02_exp(float t) {
    t = t > 0.f ? t : 0.2f * t;                        // leaky_relu(0.2)
    return __expf(t);
}

// ---------------------------------------------------------------------------
// pack0: blocks 0..15 pack W_gat, 16..19 pack W_lin, 20 zeroes bcnt.
__global__ __launch_bounds__(256) void pack0(const float* __restrict__ Wg,
                                             const float* __restrict__ Wl,
                                             u16* __restrict__ pWg,
                                             u16* __restrict__ pWl,
                                             int* __restrict__ bcnt) {
    int blk = blockIdx.x, tid = threadIdx.x;
    if (blk < 16) {
        int t = blk * 256 + tid;
        int lane = t & 63, tile = t >> 6;
        int nt = tile & 7, kt = tile >> 3;
        int col = lane & 15, quad = lane >> 4;
        int krow = kt * 32 + quad * 8;
        int ncol = nt * 16 + col;
#pragma unroll
        for (int j = 0; j < 8; j++) pWg[t * 8 + j] = f2b(Wg[(krow + j) * HID + ncol]);
    } else if (blk < 20) {
        int t = (blk - 16) * 256 + tid;
        int lane = t & 63, tile = t >> 6;
        int nt = tile & 3, kt = tile >> 2;
        int col = lane & 15, quad = lane >> 4;
        int o  = nt * 16 + col;
        int k0 = kt * 32 + quad * 8;
#pragma unroll
        for (int j = 0; j < 8; j++) pWl[t * 8 + j] = f2b(Wl[o * HID + k0 + j]);
    } else {
        if (tid < NBKT) bcnt[tid] = 0;
    }
}

// ---------------------------------------------------------------------------
// k_mega: blocks [0,GB) = feat GEMM (1 strip/wave, 16 x-loads pinned live
// via asm use-barrier, fused el/er epilogue); blocks [GB, GB+PA_NB) = edge
// partition into 196 bucket regions. Byte-identical to round 13.
__global__ __launch_bounds__(256) void k_mega(
        const float* __restrict__ x, const u16* __restrict__ pWg,
        const float* __restrict__ al_, const float* __restrict__ ar_,
        unsigned* __restrict__ feat2, float* __restrict__ el, float* __restrict__ er,
        const int* __restrict__ src, const int* __restrict__ dst,
        int* __restrict__ bcnt, u64* __restrict__ pairs) {
    __shared__ u64 smemU[21504 / 8];
    char* smem = (char*)smemU;
    int blk = blockIdx.x, tid = threadIdx.x;

    if (blk < GB) {
        // ---- feat GEMM path (no LDS use) ----
        int wave = tid >> 6, lane = tid & 63;
        int strip = blk * 4 + wave;
        if (strip >= NSTRIP) return;
        int m0 = strip * 16;
        int col = lane & 15, quad = lane >> 4;

        // hoist ALL x loads for this strip: 16 independent 16B loads/lane
        f32x4 xa[16];
        const float* xr = x + (size_t)(m0 + col) * IN_F + quad * 8;
#pragma unroll
        for (int kt = 0; kt < 8; kt++) {
            xa[2 * kt]     = *reinterpret_cast<const f32x4*>(xr + kt * 32);
            xa[2 * kt + 1] = *reinterpret_cast<const f32x4*>(xr + kt * 32 + 4);
        }
        // pin all 16 loads simultaneously resident -> burst issue, one wait
        asm volatile("" :: "v"(xa[0]), "v"(xa[1]), "v"(xa[2]), "v"(xa[3]),
                           "v"(xa[4]), "v"(xa[5]), "v"(xa[6]), "v"(xa[7]),
                           "v"(xa[8]), "v"(xa[9]), "v"(xa[10]), "v"(xa[11]),
                           "v"(xa[12]), "v"(xa[13]), "v"(xa[14]), "v"(xa[15]));
        bf16x8 av[8];
#pragma unroll
        for (int kt = 0; kt < 8; kt++)
#pragma unroll
            for (int j = 0; j < 4; j++) {
                av[kt][j]     = (__bf16)xa[2 * kt][j];
                av[kt][4 + j] = (__bf16)xa[2 * kt + 1][j];
            }

        f32x4 acc[8] = {};
#pragma unroll
        for (int kt = 0; kt < 8; kt++)
#pragma unroll
            for (int nt = 0; nt < 8; nt++) {
                bf16x8 b = *reinterpret_cast<const bf16x8*>(pWg + ((kt * 8 + nt) * 64 + lane) * 8);
                acc[nt] = __builtin_amdgcn_mfma_f32_16x16x32_bf16(av[kt], b, acc[nt], 0, 0, 0);
            }

        // epilogue: el/er dot products + bf16 feat store
        float pl[4] = {0, 0, 0, 0}, pr[4] = {0, 0, 0, 0};
#pragma unroll
        for (int nt = 0; nt < 8; nt++) {
            float alv = al_[nt * 16 + col], arv = ar_[nt * 16 + col];
#pragma unroll
            for (int reg = 0; reg < 4; reg++) {
                pl[reg] += acc[nt][reg] * alv;
                pr[reg] += acc[nt][reg] * arv;
            }
        }
#pragma unroll
        for (int m = 1; m < 16; m <<= 1)
#pragma unroll
            for (int reg = 0; reg < 4; reg++) {
                pl[reg] += __shfl_xor(pl[reg], m, 64);
                pr[reg] += __shfl_xor(pr[reg], m, 64);
            }
        if (col == 0) {
#pragma unroll
            for (int reg = 0; reg < 4; reg++) {
                el[m0 + quad * 4 + reg] = pl[reg];
                er[m0 + quad * 4 + reg] = pr[reg];
            }
        }
#pragma unroll
        for (int nt = 0; nt < 8; nt++)
#pragma unroll
            for (int reg = 0; reg < 4; reg++) {
                u16* fp = (u16*)feat2;
                fp[(size_t)(m0 + quad * 4 + reg) * HID + nt * 16 + col] = f2b(acc[nt][reg]);
            }
        return;
    }

    // ---- edge partition path ----
    int* hist    = (int*)smem;                         // 256 ints (196 used)
    int* binbase = hist + 256;
    int* gbase   = binbase + 256;
    int* fill    = gbase + 256;
    int* stmp    = fill + 256;                         // 256 ints -> 5120 B
    u64* spair   = (u64*)(smem + 5120);                // 2048 * 8 = 16384 B

    int e0 = (blk - GB) * PA_EDGES;
    int cnt = NEDGES - e0; if (cnt > PA_EDGES) cnt = PA_EDGES;

    hist[tid] = 0; fill[tid] = 0;
    __syncthreads();

    int es[PA_EPT], ed[PA_EPT];
#pragma unroll
    for (int j = 0; j < PA_EPT; j++) {
        int idx = e0 + j * 256 + tid;
        if (idx < NEDGES) {
            es[j] = src[idx];
            ed[j] = dst[idx];
            atomicAdd(&hist[ed[j] >> 8], 1);
        } else ed[j] = -1;
    }
    __syncthreads();

    stmp[tid] = (tid < NBKT) ? hist[tid] : 0;
    __syncthreads();
#pragma unroll
    for (int ofs = 1; ofs < 256; ofs <<= 1) {
        int u = (tid >= ofs) ? stmp[tid - ofs] : 0;
        __syncthreads();
        stmp[tid] += u;
        __syncthreads();
    }
    if (tid < NBKT) {
        binbase[tid] = stmp[tid] - hist[tid];
        if (hist[tid] > 0)
            gbase[tid] = tid * BCAP + atomicAdd(&bcnt[tid], hist[tid]);
    }
    __syncthreads();

#pragma unroll
    for (int j = 0; j < PA_EPT; j++) {
        if (ed[j] >= 0) {
            int b = ed[j] >> 8;
            int r = atomicAdd(&fill[b], 1);
            int loc = binbase[b] + r;
            spair[loc] = ((u64)(unsigned)ed[j] << 32) | (unsigned)es[j];
        }
    }
    __syncthreads();

    for (int i = tid; i < cnt; i += 256) {
        u64 p = spair[i];
        int b = (int)(p >> 40);                        // dst>>8 from packed pair
        pairs[gbase[b] + (i - binbase[b])] = p;
    }
}

// ---------------------------------------------------------------------------
// k_agg64: one block (512 thr, 8 waves) per 64 nodes (784 blocks,
// XCD-swizzled). 3 blocks/CU (24 waves; LDS-capped) and 784 ~= 768 resident
// -> ~1 scheduling round, no straggler tail (the 52%-occupancy fix).
// Phase A: scan coarse 256-node window once per block, filter, build
// 64x64-slot LDS lists with w inline. Phase B: 8-deep wave-per-node gather
// (8 nodes/wave), gather dwords pinned via asm. Phase C: each wave does 2
// of the 16 (tile,nt) MFMA units over the 64x64 output tile.
__global__ __launch_bounds__(512) void k_agg64(const u64* __restrict__ pairs,
                                               const int* __restrict__ bcnt,
                                               const float* __restrict__ el,
                                               const float* __restrict__ er,
                                               const unsigned* __restrict__ feat2,
                                               const float* __restrict__ bias,
                                               const u16* __restrict__ pWl,
                                               float* __restrict__ out) {
    __shared__ int   cnt_l[AGN];
    __shared__ float erl[AGN];
    __shared__ int   ssrc[AGN * AGSLOT];               // 16 KB
    __shared__ float swgt[AGN * AGSLOT];               // 16 KB
    __shared__ unsigned sg[AGN * 68];                  // 17.4 KB

    int tid = threadIdx.x;
    int wave = tid >> 6, lane = tid & 63;
    // XCD-bijective swizzle: 784 = 8 * 98.
    int logical = (blockIdx.x & 7) * 98 + (blockIdx.x >> 3);
    int nb = logical * AGN;
    if (nb >= NNODES) return;
    int cb = logical >> 2;                             // coarse 256-node bucket

    if (tid < AGN) {
        cnt_l[tid] = 0;
        int n = nb + tid;
        erl[tid] = (n < NNODES) ? er[n] : 0.f;
    }
    __syncthreads();

    // ---- phase A: filter + attention weight + LDS list build ----
    int cntb = bcnt[cb];
    const u64* reg = pairs + (size_t)cb * BCAP;
    for (int i = tid; i < cntb; i += 512) {
        u64 p = reg[i];
        int d = (int)(unsigned)(p >> 32);
        unsigned dl = (unsigned)(d - nb);
        if (dl < (unsigned)AGN) {
            int s = (int)(unsigned)(p & 0xffffffffu);
            float w = lrelu02_exp(el[s] + erl[dl]);
            int slot = atomicAdd(&cnt_l[dl], 1);
            if (slot < AGSLOT) {
                ssrc[dl * AGSLOT + slot] = s;
                swgt[dl * AGSLOT + slot] = w;
            }
        }
    }
    __syncthreads();

    // ---- phase B: wave-per-node gather + normalize (8 nodes/wave) ----
    float bl = bias[lane * 2 + 0], bh = bias[lane * 2 + 1];
    for (int i = 0; i < 8; i++) {
        int dl = wave * 8 + i;
        int cnt = cnt_l[dl]; if (cnt > AGSLOT) cnt = AGSLOT;
        const int*   ep = ssrc + dl * AGSLOT;
        const float* wp = swgt + dl * AGSLOT;

        float p0 = 0.f, p1 = 0.f, q0 = 0.f, q1 = 0.f;
        float r0 = 0.f, r1 = 0.f, t0 = 0.f, t1 = 0.f;
        float u0 = 0.f, u1 = 0.f, x0 = 0.f, x1 = 0.f;
        float y0 = 0.f, y1 = 0.f, z0 = 0.f, z1 = 0.f;
        float dn = 0.f;
        int j = 0;
        for (; j + 8 <= cnt; j += 8) {
            int4 sa = *reinterpret_cast<const int4*>(ep + j);
            int4 sb = *reinterpret_cast<const int4*>(ep + j + 4);
            float4 wa = *reinterpret_cast<const float4*>(wp + j);
            float4 wb = *reinterpret_cast<const float4*>(wp + j + 4);
            unsigned v0 = feat2[(size_t)sa.x * 64 + lane];
            unsigned v1 = feat2[(size_t)sa.y * 64 + lane];
            unsigned v2 = feat2[(size_t)sa.z * 64 + lane];
            unsigned v3 = feat2[(size_t)sa.w * 64 + lane];
            unsigned v4 = feat2[(size_t)sb.x * 64 + lane];
            unsigned v5 = feat2[(size_t)sb.y * 64 + lane];
            unsigned v6 = feat2[(size_t)sb.z * 64 + lane];
            unsigned v7 = feat2[(size_t)sb.w * 64 + lane];
            // pin all 8 gather results simultaneously resident
            asm volatile("" :: "v"(v0), "v"(v1), "v"(v2), "v"(v3),
                               "v"(v4), "v"(v5), "v"(v6), "v"(v7));
            p0 += wa.x * b2f_lo(v0); p1 += wa.x * b2f_hi(v0);
            q0 += wa.y * b2f_lo(v1); q1 += wa.y * b2f_hi(v1);
            r0 += wa.z * b2f_lo(v2); r1 += wa.z * b2f_hi(v2);
            t0 += wa.w * b2f_lo(v3); t1 += wa.w * b2f_hi(v3);
            u0 += wb.x * b2f_lo(v4); u1 += wb.x * b2f_hi(v4);
            x0 += wb.y * b2f_lo(v5); x1 += wb.y * b2f_hi(v5);
            y0 += wb.z * b2f_lo(v6); y1 += wb.z * b2f_hi(v6);
            z0 += wb.w * b2f_lo(v7); z1 += wb.w * b2f_hi(v7);
            dn += ((wa.x + wa.y) + (wa.z + wa.w)) + ((wb.x + wb.y) + (wb.z + wb.w));
        }
        if (j + 4 <= cnt) {
            int4 sa = *reinterpret_cast<const int4*>(ep + j);
            float4 wa = *reinterpret_cast<const float4*>(wp + j);
            unsigned v0 = feat2[(size_t)sa.x * 64 + lane];
            unsigned v1 = feat2[(size_t)sa.y * 64 + lane];
            unsigned v2 = feat2[(size_t)sa.z * 64 + lane];
            unsigned v3 = feat2[(size_t)sa.w * 64 + lane];
            asm volatile("" :: "v"(v0), "v"(v1), "v"(v2), "v"(v3));
            p0 += wa.x * b2f_lo(v0); p1 += wa.x * b2f_hi(v0);
            q0 += wa.y * b2f_lo(v1); q1 += wa.y * b2f_hi(v1);
            r0 += wa.z * b2f_lo(v2); r1 += wa.z * b2f_hi(v2);
            t0 += wa.w * b2f_lo(v3); t1 += wa.w * b2f_hi(v3);
            dn += (wa.x + wa.y) + (wa.z + wa.w);
            j += 4;
        }
        for (; j < cnt; j++) {
            int s = ep[j];
            float w = wp[j];
            unsigned v = feat2[(size_t)s * 64 + lane];
            p0 += w * b2f_lo(v); p1 += w * b2f_hi(v);
            dn += w;
        }
        float a0 = ((p0 + q0) + (r0 + t0)) + ((u0 + x0) + (y0 + z0));
        float a1 = ((p1 + q1) + (r1 + t1)) + ((u1 + x1) + (y1 + z1));

        float inv = dn > 0.f ? 1.f / dn : 0.f;         // isolated node -> 0
        float g0 = a0 * inv + bl;
        float g1 = a1 * inv + bh;
        g0 = g0 > 0.f ? g0 : 0.01f * g0;               // leaky_relu(0.01)
        g1 = g1 > 0.f ? g1 : 0.01f * g1;
        sg[dl * 68 + lane] = (unsigned)f2b(g0) | ((unsigned)f2b(g1) << 16);
    }
    __syncthreads();

    // ---- phase C: 64x64 output GEMM (each wave: 2 of 16 (tile,nt) units) ----
    int col = lane & 15, quad = lane >> 4;
#pragma unroll
    for (int u = 0; u < 2; u++) {
        int unit = wave * 2 + u;                       // 0..15
        int tile = unit >> 2;                          // node tile 0..3
        int nt = unit & 3;                             // output col tile 0..3
        f32x4 acc = {};
#pragma unroll
        for (int kt = 0; kt < 4; kt++) {
            bf16x8 a = *reinterpret_cast<const bf16x8*>(&sg[(tile * 16 + col) * 68 + kt * 16 + quad * 4]);
            bf16x8 bf = *reinterpret_cast<const bf16x8*>(pWl + ((kt * 4 + nt) * 64 + lane) * 8);
            acc = __builtin_amdgcn_mfma_f32_16x16x32_bf16(a, bf, acc, 0, 0, 0);
        }
#pragma unroll
        for (int reg = 0; reg < 4; reg++) {
            int row = nb + tile * 16 + quad * 4 + reg;
            if (row < NNODES)
                out[(size_t)row * OUTF + nt * 16 + col] = acc[reg];
        }
    }
}

// ---------------------------------------------------------------------------
extern "C" void kernel_launch(void* const* d_in, const int* in_sizes, int n_in,
                              void* d_out, int out_size, void* d_ws, size_t ws_size,
                              hipStream_t stream) {
    const float* x      = (const float*)d_in[0];   // [50000,256] fp32
    const int*   src    = (const int*)d_in[1];     // [800000] int32
    const int*   dst    = (const int*)d_in[2];     // [800000] int32
    const float* Wg     = (const float*)d_in[3];   // [256,128] fp32
    const float* attn_l = (const float*)d_in[4];   // [128]
    const float* attn_r = (const float*)d_in[5];   // [128]
    const float* bias   = (const float*)d_in[6];   // [128]
    const float* Wl     = (const float*)d_in[7];   // [64,128] fp32
    float* out          = (float*)d_out;           // [50000,64] fp32

    char* ws = (char*)d_ws;
    size_t off = 0;
    auto alloc = [&](size_t b) { size_t r = off; off += (b + 255) & ~(size_t)255; return r; };
    size_t pwgOff  = alloc((size_t)8 * 8 * 64 * 8 * 2);     // 64 KB
    size_t pwlOff  = alloc((size_t)4 * 4 * 64 * 8 * 2);     // 16 KB
    size_t featOff = alloc((size_t)NNODES * HID * 2);       // 12.8 MB bf16 feat
    size_t elOff   = alloc((size_t)NNODES * 4);
    size_t erOff   = alloc((size_t)NNODES * 4);
    size_t pairOff = alloc((size_t)NBKT * BCAP * 8);        // 8.0 MB bucket regions
    size_t bcntOff = alloc((size_t)NBKT * 4);

    u16*      pWg   = (u16*)(ws + pwgOff);
    u16*      pWl   = (u16*)(ws + pwlOff);
    unsigned* feat2 = (unsigned*)(ws + featOff);
    float*    el    = (float*)(ws + elOff);
    float*    er    = (float*)(ws + erOff);
    u64*      pairs = (u64*)(ws + pairOff);
    int*      bcnt  = (int*)(ws + bcntOff);

    pack0<<<21, 256, 0, stream>>>(Wg, Wl, pWg, pWl, bcnt);
    k_mega<<<GB + PA_NB, 256, 0, stream>>>(x, pWg, attn_l, attn_r, feat2, el, er,
                                           src, dst, bcnt, pairs);
    k_agg64<<<AGB, 512, 0, stream>>>(pairs, bcnt, el, er, feat2, bias,
                                     pWl, out);
}

// Round 16
// 154.508 us; speedup vs baseline: 1.0802x; 1.0802x over previous
//
#include <hip/hip_runtime.h>
#include <hip/hip_bf16.h>

// GAT layer on MI355X. Round 31: RESUBMIT of round 30 (container infra
// failure, no measurement; audit found no fault). k_mega B-side LDS
// staging. Round-14's 512-thr agg was falsified (occupancy DROPPED 52->35,
// dur 42->53) -> k_agg64 reverted to round-13 1024-thr (best wall 158.1).
// Target: k_mega's never-addressed serial term -- 64 per-fragment pWg loads
// from L2 per wave, compiler-rolled to MLP ~2-4 (the VGPR-32 behavior)
// = ~4000cy exposed L2 latency/wave = the "nothing busy" profile (VALU 4%,
// MFMA 2%, HBM 14%). Fix: stage pWg in 4 x 16KB LDS chunks per block
// (reg-staged, MLP 4x256 thr), barrier, MFMA reads ds_read_b128 (2-way
// banks = free), barrier. Chunks fit the EXISTING 21504B smem -> 7
// blocks/CU unchanged; staged data shared by all 4 waves (4x less L2
// traffic). Early-return waves -> valid-guarded (all waves hit barriers).
// k_agg64/pack0/partition byte-identical to round 13. 3 dispatches.

#define NNODES 50000
#define NEDGES 800000
#define IN_F   256
#define HID    128
#define OUTF   64

#define PA_EPT   8
#define PA_EDGES (256 * PA_EPT)                          // 2048 edges/block
#define PA_NB    ((NEDGES + PA_EDGES - 1) / PA_EDGES)    // 391 blocks
#define NBKT     ((NNODES + 255) / 256)                  // 196 buckets (dst>>8)
#define BCAP     5120                                    // bucket capacity (lam=4082)
#define NSTRIP   (NNODES / 16)                           // 3125 strips
#define GB       ((NSTRIP + 3) / 4)                      // 782 gemm blocks

#define AGN      64                                      // nodes per agg block
#define AGSLOT   64                                      // per-node LDS slot cap (max deg ~45)
#define AGB      784                                     // 8 * 98 agg blocks (>= 782)

typedef unsigned short u16;
typedef unsigned long long u64;
typedef __bf16 bf16x8 __attribute__((ext_vector_type(8)));
typedef float  f32x4  __attribute__((ext_vector_type(4)));

__device__ __forceinline__ u16 f2b(float f) {
    union { float f; unsigned u; } v; v.f = f;
    unsigned u = v.u;
    return (u16)((u + 0x7fffu + ((u >> 16) & 1u)) >> 16);  // RNE fp32->bf16
}
__device__ __forceinline__ float b2f_lo(unsigned v) {
    union { unsigned u; float f; } c; c.u = (v & 0xffffu) << 16; return c.f;
}
__device__ __forceinline__ float b2f_hi(unsigned v) {
    union { unsigned u; float f; } c; c.u = v & 0xffff0000u; return c.f;
}
__device__ __forceinline__ float lrelu02_exp(float t) {
    t = t > 0.f ? t : 0.2f * t;                        // leaky_relu(0.2)
    return __expf(t);
}

// ---------------------------------------------------------------------------
// pack0: blocks 0..15 pack W_gat, 16..19 pack W_lin, 20 zeroes bcnt.
__global__ __launch_bounds__(256) void pack0(const float* __restrict__ Wg,
                                             const float* __restrict__ Wl,
                                             u16* __restrict__ pWg,
                                             u16* __restrict__ pWl,
                                             int* __restrict__ bcnt) {
    int blk = blockIdx.x, tid = threadIdx.x;
    if (blk < 16) {
        int t = blk * 256 + tid;
        int lane = t & 63, tile = t >> 6;
        int nt = tile & 7, kt = tile >> 3;
        int col = lane & 15, quad = lane >> 4;
        int krow = kt * 32 + quad * 8;
        int ncol = nt * 16 + col;
#pragma unroll
        for (int j = 0; j < 8; j++) pWg[t * 8 + j] = f2b(Wg[(krow + j) * HID + ncol]);
    } else if (blk < 20) {
        int t = (blk - 16) * 256 + tid;
        int lane = t & 63, tile = t >> 6;
        int nt = tile & 3, kt = tile >> 2;
        int col = lane & 15, quad = lane >> 4;
        int o  = nt * 16 + col;
        int k0 = kt * 32 + quad * 8;
#pragma unroll
        for (int j = 0; j < 8; j++) pWl[t * 8 + j] = f2b(Wl[o * HID + k0 + j]);
    } else {
        if (tid < NBKT) bcnt[tid] = 0;
    }
}

// ---------------------------------------------------------------------------
// k_mega: blocks [0,GB) = feat GEMM (1 strip/wave, 16 x-loads pinned,
// B-side pWg staged via LDS in 4 x 16KB chunks); blocks [GB, GB+PA_NB) =
// edge partition into 196 bucket regions.
__global__ __launch_bounds__(256) void k_mega(
        const float* __restrict__ x, const u16* __restrict__ pWg,
        const float* __restrict__ al_, const float* __restrict__ ar_,
        unsigned* __restrict__ feat2, float* __restrict__ el, float* __restrict__ er,
        const int* __restrict__ src, const int* __restrict__ dst,
        int* __restrict__ bcnt, u64* __restrict__ pairs) {
    __shared__ u64 smemU[21504 / 8];
    char* smem = (char*)smemU;
    int blk = blockIdx.x, tid = threadIdx.x;

    if (blk < GB) {
        // ---- feat GEMM path (LDS = 16KB weight chunk buffer) ----
        int wave = tid >> 6, lane = tid & 63;
        int strip = blk * 4 + wave;
        bool valid = (strip < NSTRIP);                 // wave-uniform
        int m0 = strip * 16;
        int col = lane & 15, quad = lane >> 4;

        // hoist ALL x loads for this strip: 16 independent 16B loads/lane
        f32x4 xa[16];
        if (valid) {
            const float* xr = x + (size_t)(m0 + col) * IN_F + quad * 8;
#pragma unroll
            for (int kt = 0; kt < 8; kt++) {
                xa[2 * kt]     = *reinterpret_cast<const f32x4*>(xr + kt * 32);
                xa[2 * kt + 1] = *reinterpret_cast<const f32x4*>(xr + kt * 32 + 4);
            }
            asm volatile("" :: "v"(xa[0]), "v"(xa[1]), "v"(xa[2]), "v"(xa[3]),
                               "v"(xa[4]), "v"(xa[5]), "v"(xa[6]), "v"(xa[7]),
                               "v"(xa[8]), "v"(xa[9]), "v"(xa[10]), "v"(xa[11]),
                               "v"(xa[12]), "v"(xa[13]), "v"(xa[14]), "v"(xa[15]));
        }
        bf16x8 av[8];
        if (valid) {
#pragma unroll
            for (int kt = 0; kt < 8; kt++)
#pragma unroll
                for (int j = 0; j < 4; j++) {
                    av[kt][j]     = (__bf16)xa[2 * kt][j];
                    av[kt][4 + j] = (__bf16)xa[2 * kt + 1][j];
                }
        }

        f32x4 acc[8] = {};
        // 4 chunks of 16KB: fragments (kt*8+nt) for kt in {2c, 2c+1}
        for (int c = 0; c < 4; c++) {
            // stage chunk c: 16KB, 64B per thread (4 x 16B, MLP 4)
#pragma unroll
            for (int i = 0; i < 4; i++) {
                f32x4 w = *reinterpret_cast<const f32x4*>(
                    (const char*)pWg + c * 16384 + i * 4096 + tid * 16);
                *reinterpret_cast<f32x4*>(smem + i * 4096 + tid * 16) = w;
            }
            __syncthreads();
            if (valid) {
#pragma unroll
                for (int kt2 = 0; kt2 < 2; kt2++) {
                    int kt = c * 2 + kt2;
#pragma unroll
                    for (int nt = 0; nt < 8; nt++) {
                        bf16x8 b = *reinterpret_cast<const bf16x8*>(
                            smem + ((kt2 * 8 + nt) * 64 + lane) * 16);
                        acc[nt] = __builtin_amdgcn_mfma_f32_16x16x32_bf16(av[kt], b, acc[nt], 0, 0, 0);
                    }
                }
            }
            __syncthreads();
        }

        if (!valid) return;
        // epilogue: el/er dot products + bf16 feat store
        float pl[4] = {0, 0, 0, 0}, pr[4] = {0, 0, 0, 0};
#pragma unroll
        for (int nt = 0; nt < 8; nt++) {
            float alv = al_[nt * 16 + col], arv = ar_[nt * 16 + col];
#pragma unroll
            for (int reg = 0; reg < 4; reg++) {
                pl[reg] += acc[nt][reg] * alv;
                pr[reg] += acc[nt][reg] * arv;
            }
        }
#pragma unroll
        for (int m = 1; m < 16; m <<= 1)
#pragma unroll
            for (int reg = 0; reg < 4; reg++) {
                pl[reg] += __shfl_xor(pl[reg], m, 64);
                pr[reg] += __shfl_xor(pr[reg], m, 64);
            }
        if (col == 0) {
#pragma unroll
            for (int reg = 0; reg < 4; reg++) {
                el[m0 + quad * 4 + reg] = pl[reg];
                er[m0 + quad * 4 + reg] = pr[reg];
            }
        }
#pragma unroll
        for (int nt = 0; nt < 8; nt++)
#pragma unroll
            for (int reg = 0; reg < 4; reg++) {
                u16* fp = (u16*)feat2;
                fp[(size_t)(m0 + quad * 4 + reg) * HID + nt * 16 + col] = f2b(acc[nt][reg]);
            }
        return;
    }

    // ---- edge partition path ----
    int* hist    = (int*)smem;                         // 256 ints (196 used)
    int* binbase = hist + 256;
    int* gbase   = binbase + 256;
    int* fill    = gbase + 256;
    int* stmp    = fill + 256;                         // 256 ints -> 5120 B
    u64* spair   = (u64*)(smem + 5120);                // 2048 * 8 = 16384 B

    int e0 = (blk - GB) * PA_EDGES;
    int cnt = NEDGES - e0; if (cnt > PA_EDGES) cnt = PA_EDGES;

    hist[tid] = 0; fill[tid] = 0;
    __syncthreads();

    int es[PA_EPT], ed[PA_EPT];
#pragma unroll
    for (int j = 0; j < PA_EPT; j++) {
        int idx = e0 + j * 256 + tid;
        if (idx < NEDGES) {
            es[j] = src[idx];
            ed[j] = dst[idx];
            atomicAdd(&hist[ed[j] >> 8], 1);
        } else ed[j] = -1;
    }
    __syncthreads();

    stmp[tid] = (tid < NBKT) ? hist[tid] : 0;
    __syncthreads();
#pragma unroll
    for (int ofs = 1; ofs < 256; ofs <<= 1) {
        int u = (tid >= ofs) ? stmp[tid - ofs] : 0;
        __syncthreads();
        stmp[tid] += u;
        __syncthreads();
    }
    if (tid < NBKT) {
        binbase[tid] = stmp[tid] - hist[tid];
        if (hist[tid] > 0)
            gbase[tid] = tid * BCAP + atomicAdd(&bcnt[tid], hist[tid]);
    }
    __syncthreads();

#pragma unroll
    for (int j = 0; j < PA_EPT; j++) {
        if (ed[j] >= 0) {
            int b = ed[j] >> 8;
            int r = atomicAdd(&fill[b], 1);
            int loc = binbase[b] + r;
            spair[loc] = ((u64)(unsigned)ed[j] << 32) | (unsigned)es[j];
        }
    }
    __syncthreads();

    for (int i = tid; i < cnt; i += 256) {
        u64 p = spair[i];
        int b = (int)(p >> 40);                        // dst>>8 from packed pair
        pairs[gbase[b] + (i - binbase[b])] = p;
    }
}

// ---------------------------------------------------------------------------
// k_agg64: one block (1024 thr, 16 waves) per 64 nodes (784 blocks,
// XCD-swizzled). Phase A: scan the coarse 256-node window once per block,
// filter, build 64x64-slot LDS lists with w inline. Phase B: 8-deep
// wave-per-node gather (4 nodes/wave), gather dwords pinned via asm.
// Phase C: 16 waves = 4 node-tiles x 4 nt over the 64x64 output tile.
// (round-13 version verbatim -- round-14's 512-thr variant regressed.)
__global__ __launch_bounds__(1024) void k_agg64(const u64* __restrict__ pairs,
                                                const int* __restrict__ bcnt,
                                                const float* __restrict__ el,
                                                const float* __restrict__ er,
                                                const unsigned* __restrict__ feat2,
                                                const float* __restrict__ bias,
                                                const u16* __restrict__ pWl,
                                                float* __restrict__ out) {
    __shared__ int   cnt_l[AGN];
    __shared__ float erl[AGN];
    __shared__ int   ssrc[AGN * AGSLOT];               // 16 KB
    __shared__ float swgt[AGN * AGSLOT];               // 16 KB
    __shared__ unsigned sg[AGN * 68];                  // 17.4 KB

    int tid = threadIdx.x;
    int wave = tid >> 6, lane = tid & 63;
    // XCD-bijective swizzle: 784 = 8 * 98.
    int logical = (blockIdx.x & 7) * 98 + (blockIdx.x >> 3);
    int nb = logical * AGN;
    if (nb >= NNODES) return;
    int cb = logical >> 2;                             // coarse 256-node bucket

    if (tid < AGN) {
        cnt_l[tid] = 0;
        int n = nb + tid;
        erl[tid] = (n < NNODES) ? er[n] : 0.f;
    }
    __syncthreads();

    // ---- phase A: filter + attention weight + LDS list build ----
    int cntb = bcnt[cb];
    const u64* reg = pairs + (size_t)cb * BCAP;
    for (int i = tid; i < cntb; i += 1024) {
        u64 p = reg[i];
        int d = (int)(unsigned)(p >> 32);
        unsigned dl = (unsigned)(d - nb);
        if (dl < (unsigned)AGN) {
            int s = (int)(unsigned)(p & 0xffffffffu);
            float w = lrelu02_exp(el[s] + erl[dl]);
            int slot = atomicAdd(&cnt_l[dl], 1);
            if (slot < AGSLOT) {
                ssrc[dl * AGSLOT + slot] = s;
                swgt[dl * AGSLOT + slot] = w;
            }
        }
    }
    __syncthreads();

    // ---- phase B: wave-per-node gather + normalize ----
    float bl = bias[lane * 2 + 0], bh = bias[lane * 2 + 1];
    for (int i = 0; i < 4; i++) {
        int dl = wave * 4 + i;
        int cnt = cnt_l[dl]; if (cnt > AGSLOT) cnt = AGSLOT;
        const int*   ep = ssrc + dl * AGSLOT;
        const float* wp = swgt + dl * AGSLOT;

        float p0 = 0.f, p1 = 0.f, q0 = 0.f, q1 = 0.f;
        float r0 = 0.f, r1 = 0.f, t0 = 0.f, t1 = 0.f;
        float u0 = 0.f, u1 = 0.f, x0 = 0.f, x1 = 0.f;
        float y0 = 0.f, y1 = 0.f, z0 = 0.f, z1 = 0.f;
        float dn = 0.f;
        int j = 0;
        for (; j + 8 <= cnt; j += 8) {
            int4 sa = *reinterpret_cast<const int4*>(ep + j);
            int4 sb = *reinterpret_cast<const int4*>(ep + j + 4);
            float4 wa = *reinterpret_cast<const float4*>(wp + j);
            float4 wb = *reinterpret_cast<const float4*>(wp + j + 4);
            unsigned v0 = feat2[(size_t)sa.x * 64 + lane];
            unsigned v1 = feat2[(size_t)sa.y * 64 + lane];
            unsigned v2 = feat2[(size_t)sa.z * 64 + lane];
            unsigned v3 = feat2[(size_t)sa.w * 64 + lane];
            unsigned v4 = feat2[(size_t)sb.x * 64 + lane];
            unsigned v5 = feat2[(size_t)sb.y * 64 + lane];
            unsigned v6 = feat2[(size_t)sb.z * 64 + lane];
            unsigned v7 = feat2[(size_t)sb.w * 64 + lane];
            // pin all 8 gather results simultaneously resident
            asm volatile("" :: "v"(v0), "v"(v1), "v"(v2), "v"(v3),
                               "v"(v4), "v"(v5), "v"(v6), "v"(v7));
            p0 += wa.x * b2f_lo(v0); p1 += wa.x * b2f_hi(v0);
            q0 += wa.y * b2f_lo(v1); q1 += wa.y * b2f_hi(v1);
            r0 += wa.z * b2f_lo(v2); r1 += wa.z * b2f_hi(v2);
            t0 += wa.w * b2f_lo(v3); t1 += wa.w * b2f_hi(v3);
            u0 += wb.x * b2f_lo(v4); u1 += wb.x * b2f_hi(v4);
            x0 += wb.y * b2f_lo(v5); x1 += wb.y * b2f_hi(v5);
            y0 += wb.z * b2f_lo(v6); y1 += wb.z * b2f_hi(v6);
            z0 += wb.w * b2f_lo(v7); z1 += wb.w * b2f_hi(v7);
            dn += ((wa.x + wa.y) + (wa.z + wa.w)) + ((wb.x + wb.y) + (wb.z + wb.w));
        }
        if (j + 4 <= cnt) {
            int4 sa = *reinterpret_cast<const int4*>(ep + j);
            float4 wa = *reinterpret_cast<const float4*>(wp + j);
            unsigned v0 = feat2[(size_t)sa.x * 64 + lane];
            unsigned v1 = feat2[(size_t)sa.y * 64 + lane];
            unsigned v2 = feat2[(size_t)sa.z * 64 + lane];
            unsigned v3 = feat2[(size_t)sa.w * 64 + lane];
            asm volatile("" :: "v"(v0), "v"(v1), "v"(v2), "v"(v3));
            p0 += wa.x * b2f_lo(v0); p1 += wa.x * b2f_hi(v0);
            q0 += wa.y * b2f_lo(v1); q1 += wa.y * b2f_hi(v1);
            r0 += wa.z * b2f_lo(v2); r1 += wa.z * b2f_hi(v2);
            t0 += wa.w * b2f_lo(v3); t1 += wa.w * b2f_hi(v3);
            dn += (wa.x + wa.y) + (wa.z + wa.w);
            j += 4;
        }
        for (; j < cnt; j++) {
            int s = ep[j];
            float w = wp[j];
            unsigned v = feat2[(size_t)s * 64 + lane];
            p0 += w * b2f_lo(v); p1 += w * b2f_hi(v);
            dn += w;
        }
        float a0 = ((p0 + q0) + (r0 + t0)) + ((u0 + x0) + (y0 + z0));
        float a1 = ((p1 + q1) + (r1 + t1)) + ((u1 + x1) + (y1 + z1));

        float inv = dn > 0.f ? 1.f / dn : 0.f;         // isolated node -> 0
        float g0 = a0 * inv + bl;
        float g1 = a1 * inv + bh;
        g0 = g0 > 0.f ? g0 : 0.01f * g0;               // leaky_relu(0.01)
        g1 = g1 > 0.f ? g1 : 0.01f * g1;
        sg[dl * 68 + lane] = (unsigned)f2b(g0) | ((unsigned)f2b(g1) << 16);
    }
    __syncthreads();

    // ---- phase C: 64x64 output GEMM (wave = node-tile x nt) ----
    int col = lane & 15, quad = lane >> 4;
    int tile = wave >> 2;                              // node tile 0..3
    int nt = wave & 3;                                 // output col tile 0..3
    f32x4 acc = {};
#pragma unroll
    for (int kt = 0; kt < 4; kt++) {
        bf16x8 a = *reinterpret_cast<const bf16x8*>(&sg[(tile * 16 + col) * 68 + kt * 16 + quad * 4]);
        bf16x8 bf = *reinterpret_cast<const bf16x8*>(pWl + ((kt * 4 + nt) * 64 + lane) * 8);
        acc = __builtin_amdgcn_mfma_f32_16x16x32_bf16(a, bf, acc, 0, 0, 0);
    }
#pragma unroll
    for (int reg = 0; reg < 4; reg++) {
        int row = nb + tile * 16 + quad * 4 + reg;
        if (row < NNODES)
            out[(size_t)row * OUTF + nt * 16 + col] = acc[reg];
    }
}

// ---------------------------------------------------------------------------
extern "C" void kernel_launch(void* const* d_in, const int* in_sizes, int n_in,
                              void* d_out, int out_size, void* d_ws, size_t ws_size,
                              hipStream_t stream) {
    const float* x      = (const float*)d_in[0];   // [50000,256] fp32
    const int*   src    = (const int*)d_in[1];     // [800000] int32
    const int*   dst    = (const int*)d_in[2];     // [800000] int32
    const float* Wg     = (const float*)d_in[3];   // [256,128] fp32
    const float* attn_l = (const float*)d_in[4];   // [128]
    const float* attn_r = (const float*)d_in[5];   // [128]
    const float* bias   = (const float*)d_in[6];   // [128]
    const float* Wl     = (const float*)d_in[7];   // [64,128] fp32
    float* out          = (float*)d_out;           // [50000,64] fp32

    char* ws = (char*)d_ws;
    size_t off = 0;
    auto alloc = [&](size_t b) { size_t r = off; off += (b + 255) & ~(size_t)255; return r; };
    size_t pwgOff  = alloc((size_t)8 * 8 * 64 * 8 * 2);     // 64 KB
    size_t pwlOff  = alloc((size_t)4 * 4 * 64 * 8 * 2);     // 16 KB
    size_t featOff = alloc((size_t)NNODES * HID * 2);       // 12.8 MB bf16 feat
    size_t elOff   = alloc((size_t)NNODES * 4);
    size_t erOff   = alloc((size_t)NNODES * 4);
    size_t pairOff = alloc((size_t)NBKT * BCAP * 8);        // 8.0 MB bucket regions
    size_t bcntOff = alloc((size_t)NBKT * 4);

    u16*      pWg   = (u16*)(ws + pwgOff);
    u16*      pWl   = (u16*)(ws + pwlOff);
    unsigned* feat2 = (unsigned*)(ws + featOff);
    float*    el    = (float*)(ws + elOff);
    float*    er    = (float*)(ws + erOff);
    u64*      pairs = (u64*)(ws + pairOff);
    int*      bcnt  = (int*)(ws + bcntOff);

    pack0<<<21, 256, 0, stream>>>(Wg, Wl, pWg, pWl, bcnt);
    k_mega<<<GB + PA_NB, 256, 0, stream>>>(x, pWg, attn_l, attn_r, feat2, el, er,
                                           src, dst, bcnt, pairs);
    k_agg64<<<AGB, 1024, 0, stream>>>(pairs, bcnt, el, er, feat2, bias,
                                      pWl, out);
}